// Round 2
// baseline (942.508 us; speedup 1.0000x reference)
//
#include <hip/hip_runtime.h>

typedef __bf16 bf16_t;
typedef bf16_t bf16x8 __attribute__((ext_vector_type(8)));
typedef float f32x4 __attribute__((ext_vector_type(4)));

#define EPI_STORE 0
#define EPI_GELU 1
#define EPI_RES_WIN 2
#define EPI_RES_ID 3

__device__ __forceinline__ float bf2f(unsigned short u) {
    union { unsigned int i; float f; } x; x.i = ((unsigned int)u) << 16; return x.f;
}
__device__ __forceinline__ unsigned short f2bf(float f) {
    union { float f; unsigned int u; } x; x.f = f;
    unsigned int u = x.u;
    return (unsigned short)((u + 0x7fffu + ((u >> 16) & 1u)) >> 16);
}

// window-layout row m (0..32767) -> image-layout row (b*4096 + l), folding the
// roll(-shift) + window partition. Same map serves gather (QKV) and scatter (proj).
__device__ __forceinline__ int map_win(int m, int shift) {
    int n = m & 63, w = m >> 6;
    int b = w >> 6, ww = w & 63;
    int hh = ((ww >> 3) * 8 + (n >> 3) + shift) & 63;
    int wc = ((ww & 7) * 8 + (n & 7) + shift) & 63;
    return (b << 12) + (hh << 6) + wc;
}

// ---------------- small kernels ----------------

__global__ void f2bf_kernel(const float* __restrict__ in,
                            unsigned short* __restrict__ out, int n) {
    int i = blockIdx.x * 256 + threadIdx.x;
    if (i < n) out[i] = f2bf(in[i]);
}

__global__ void x_init_kernel(const float* __restrict__ xin,
                              float* __restrict__ xc, int n) {
    int i = blockIdx.x * 256 + threadIdx.x;
    if (i < n) xc[i] = xin[i];
}

__global__ void silu_kernel(const float* __restrict__ emb,
                            float* __restrict__ out, int n) {
    int i = blockIdx.x * 256 + threadIdx.x;
    if (i < n) { float e = emb[i]; out[i] = e / (1.0f + expf(-e)); }
}

// ada[layer][b][j] = silu(emb[b]) . ada_w[layer][j] + ada_b[layer][j]
__global__ __launch_bounds__(64) void ada_kernel(
    const float* __restrict__ se,           // [8][384] silu(emb)
    const float* __restrict__ ada_w,        // [2][2304][384]
    const float* __restrict__ ada_b,        // [2][2304]
    float* __restrict__ ada_out)            // [2][8][2304]
{
    int j = blockIdx.x;          // 0..2303
    int layer = blockIdx.y;      // 0..1
    int t = threadIdx.x;
    const float* wr = ada_w + ((long)layer * 2304 + j) * 384;
    float w[6];
#pragma unroll
    for (int q = 0; q < 6; q++) w[q] = wr[t + 64 * q];
    float bias = ada_b[layer * 2304 + j];
    for (int b = 0; b < 8; b++) {
        float p = 0.f;
#pragma unroll
        for (int q = 0; q < 6; q++) p += se[b * 384 + t + 64 * q] * w[q];
#pragma unroll
        for (int o = 32; o > 0; o >>= 1) p += __shfl_xor(p, o);
        if (t == 0) ada_out[((long)layer * 8 + b) * 2304 + j] = p + bias;
    }
}

// LayerNorm + adaLN modulate: h = LN(x)*(1+sc) + sh, bf16 out, image layout
__global__ __launch_bounds__(64) void ln_mod_kernel(
    const float* __restrict__ x, const float* __restrict__ ada,  // layer base [8][2304]
    unsigned short* __restrict__ h, int sh_off, int sc_off)
{
    int row = blockIdx.x;        // 0..32767 (b*4096 + l)
    int b = row >> 12;
    int t = threadIdx.x;
    const float* xr = x + (long)row * 384;
    float v[6];
    float s = 0.f;
#pragma unroll
    for (int j = 0; j < 6; j++) { v[j] = xr[t + 64 * j]; s += v[j]; }
#pragma unroll
    for (int o = 32; o > 0; o >>= 1) s += __shfl_xor(s, o);
    float mean = s * (1.0f / 384.0f);
    float s2 = 0.f;
#pragma unroll
    for (int j = 0; j < 6; j++) { float d = v[j] - mean; s2 += d * d; }
#pragma unroll
    for (int o = 32; o > 0; o >>= 1) s2 += __shfl_xor(s2, o);
    float rstd = rsqrtf(s2 * (1.0f / 384.0f) + 1e-6f);
    const float* adab = ada + (long)b * 2304;
#pragma unroll
    for (int j = 0; j < 6; j++) {
        int c = t + 64 * j;
        float val = (v[j] - mean) * rstd * (1.0f + adab[sc_off + c]) + adab[sh_off + c];
        h[(long)row * 384 + c] = f2bf(val);
    }
}

// ---------------- GEMM: out[M,N] = A[M,K] @ W[N,K]^T + bias, epilogue variants ----
// 128x128 tile, BK=32, 256 threads = 4 waves, each wave does 64x64 via 4x4 MFMA tiles.

template <int EPI, bool GATHER>
__global__ __launch_bounds__(256) void gemm128(
    const unsigned short* __restrict__ A,
    const unsigned short* __restrict__ W,
    const float* __restrict__ bias,
    unsigned short* __restrict__ out,
    float* __restrict__ xres,
    const float* __restrict__ gvec,   // [8][2304] stride, pre-offset to the g split
    int M, int N, int K, int shift)
{
    __shared__ __align__(16) unsigned short As[128 * 32];
    __shared__ __align__(16) unsigned short Bs[128 * 32];

    const int tid = threadIdx.x;
    const int m0 = blockIdx.y * 128, n0 = blockIdx.x * 128;

    // staging assignments: 512 16B-chunks per tile, 2 per thread
    const int arow0 = tid >> 2, akc0 = (tid & 3) * 8;
    const int c1 = tid + 256;
    const int arow1 = c1 >> 2, akc1 = (c1 & 3) * 8;
    const long asrc0 = GATHER ? (long)map_win(m0 + arow0, shift) : (long)(m0 + arow0);
    const long asrc1 = GATHER ? (long)map_win(m0 + arow1, shift) : (long)(m0 + arow1);
    const long bsrc0 = (long)(n0 + arow0);
    const long bsrc1 = (long)(n0 + arow1);

    const int wv = tid >> 6, lane = tid & 63;
    const int wm = (wv >> 1) * 64, wn = (wv & 1) * 64;
    const int l16 = lane & 15, quad = lane >> 4;

    f32x4 acc[4][4] = {};

    for (int k0 = 0; k0 < K; k0 += 32) {
        *(uint4*)&As[arow0 * 32 + akc0] = *(const uint4*)&A[asrc0 * K + k0 + akc0];
        *(uint4*)&As[arow1 * 32 + akc1] = *(const uint4*)&A[asrc1 * K + k0 + akc1];
        *(uint4*)&Bs[arow0 * 32 + akc0] = *(const uint4*)&W[bsrc0 * K + k0 + akc0];
        *(uint4*)&Bs[arow1 * 32 + akc1] = *(const uint4*)&W[bsrc1 * K + k0 + akc1];
        __syncthreads();

        bf16x8 af[4], bfr[4];
#pragma unroll
        for (int i = 0; i < 4; i++)
            af[i] = *(const bf16x8*)&As[(wm + i * 16 + l16) * 32 + quad * 8];
#pragma unroll
        for (int i = 0; i < 4; i++)
            bfr[i] = *(const bf16x8*)&Bs[(wn + i * 16 + l16) * 32 + quad * 8];
#pragma unroll
        for (int i = 0; i < 4; i++)
#pragma unroll
            for (int j = 0; j < 4; j++)
                acc[i][j] = __builtin_amdgcn_mfma_f32_16x16x32_bf16(af[i], bfr[j], acc[i][j], 0, 0, 0);
        __syncthreads();
    }

#pragma unroll
    for (int i = 0; i < 4; i++) {
#pragma unroll
        for (int j = 0; j < 4; j++) {
            int col = n0 + wn + j * 16 + l16;
            float bv = bias[col];
#pragma unroll
            for (int r = 0; r < 4; r++) {
                int row = m0 + wm + i * 16 + quad * 4 + r;
                float v = acc[i][j][r] + bv;
                if constexpr (EPI == EPI_STORE) {
                    out[(long)row * N + col] = f2bf(v);
                } else if constexpr (EPI == EPI_GELU) {
                    v = 0.5f * v * (1.0f + erff(v * 0.70710678118f));
                    out[(long)row * N + col] = f2bf(v);
                } else {
                    long dst = (EPI == EPI_RES_WIN) ? (long)map_win(row, shift) : (long)row;
                    int b = (int)(dst >> 12);
                    xres[dst * 384 + col] += gvec[(long)b * 2304 + col] * v;
                }
            }
        }
    }
}

// ---------------- attention: one wave per (window, head) ----------------

__device__ __forceinline__ int reg3(int p) { return (p < 56) ? 0 : ((p < 60) ? 1 : 2); }

__global__ __launch_bounds__(64) void attn_kernel(
    const unsigned short* __restrict__ qkv,        // [32768][1152] window layout, bf16
    const float* __restrict__ bias_table,          // layer base [225][12], f32
    unsigned short* __restrict__ out,              // [32768][384] window layout, bf16
    int shift)
{
    __shared__ __align__(16) float ks[64][32];
    __shared__ __align__(16) float vs[64][32];
    const int head = blockIdx.x;   // 0..11
    const int win = blockIdx.y;    // 0..511
    const int n = threadIdx.x;     // 0..63 query row

    const long rowbase = ((long)win * 64 + n) * 1152 + head * 32;
    {
        const uint4* kp = (const uint4*)(qkv + rowbase + 384);
        const uint4* vp = (const uint4*)(qkv + rowbase + 768);
#pragma unroll
        for (int c = 0; c < 4; c++) {
            uint4 kq = kp[c], vq = vp[c];
            const unsigned int ku[4] = {kq.x, kq.y, kq.z, kq.w};
            const unsigned int vu[4] = {vq.x, vq.y, vq.z, vq.w};
#pragma unroll
            for (int e = 0; e < 4; e++) {
                ks[n][c * 8 + e * 2]     = bf2f((unsigned short)(ku[e] & 0xffff));
                ks[n][c * 8 + e * 2 + 1] = bf2f((unsigned short)(ku[e] >> 16));
                vs[n][c * 8 + e * 2]     = bf2f((unsigned short)(vu[e] & 0xffff));
                vs[n][c * 8 + e * 2 + 1] = bf2f((unsigned short)(vu[e] >> 16));
            }
        }
    }
    float q[32];
    {
        const uint4* qp = (const uint4*)(qkv + rowbase);
#pragma unroll
        for (int c = 0; c < 4; c++) {
            uint4 qq = qp[c];
            const unsigned int qu[4] = {qq.x, qq.y, qq.z, qq.w};
#pragma unroll
            for (int e = 0; e < 4; e++) {
                q[c * 8 + e * 2] = bf2f((unsigned short)(qu[e] & 0xffff));
                q[c * 8 + e * 2 + 1] = bf2f((unsigned short)(qu[e] >> 16));
            }
        }
    }
    __syncthreads();

    const float scale = 0.17677669529663687f;  // 1/sqrt(32)
    const int r1 = n >> 3, c1 = n & 7;
    const int ww = win & 63;
    const int wi = ww >> 3, wj = ww & 7;
    int labq = 0;
    if (shift > 0) labq = reg3(wi * 8 + r1) * 3 + reg3(wj * 8 + c1);

    float s[64];
#pragma unroll
    for (int m = 0; m < 64; m++) {
        const float4* kr = (const float4*)ks[m];
        float d0 = 0.f;
#pragma unroll
        for (int c = 0; c < 8; c++) {
            float4 kk = kr[c];
            d0 += q[c * 4 + 0] * kk.x + q[c * 4 + 1] * kk.y +
                  q[c * 4 + 2] * kk.z + q[c * 4 + 3] * kk.w;
        }
        float sm = d0 * scale;
        int r2 = m >> 3, c2 = m & 7;
        int idx = (r1 - r2 + 7) * 15 + (c1 - c2 + 7);
        sm += bias_table[idx * 12 + head];
        if (shift > 0) {
            int labm = reg3(wi * 8 + r2) * 3 + reg3(wj * 8 + c2);
            if (labm != labq) sm -= 100.0f;
        }
        s[m] = sm;
    }
    float mx = -1e30f;
#pragma unroll
    for (int m = 0; m < 64; m++) mx = fmaxf(mx, s[m]);
    float sum = 0.f;
#pragma unroll
    for (int m = 0; m < 64; m++) { s[m] = __expf(s[m] - mx); sum += s[m]; }
    float inv = 1.0f / sum;

    float o[32] = {};
#pragma unroll
    for (int m = 0; m < 64; m++) {
        float p = s[m] * inv;
        const float4* vr = (const float4*)vs[m];
#pragma unroll
        for (int c = 0; c < 8; c++) {
            float4 vv = vr[c];
            o[c * 4 + 0] += p * vv.x; o[c * 4 + 1] += p * vv.y;
            o[c * 4 + 2] += p * vv.z; o[c * 4 + 3] += p * vv.w;
        }
    }
    unsigned short* op = out + ((long)win * 64 + n) * 384 + head * 32;
#pragma unroll
    for (int d = 0; d < 32; d++) op[d] = f2bf(o[d]);
}

// ---------------- launch ----------------

extern "C" void kernel_launch(void* const* d_in, const int* in_sizes, int n_in,
                              void* d_out, int out_size, void* d_ws, size_t ws_size,
                              hipStream_t stream) {
    const float* x_in   = (const float*)d_in[0];
    const float* emb    = (const float*)d_in[3];
    const float* qkv_w  = (const float*)d_in[4];
    const float* qkv_b  = (const float*)d_in[5];
    const float* proj_w = (const float*)d_in[6];
    const float* proj_b = (const float*)d_in[7];
    const float* ff1_w  = (const float*)d_in[8];
    const float* ff1_b  = (const float*)d_in[9];
    const float* ff2_w  = (const float*)d_in[10];
    const float* ff2_b  = (const float*)d_in[11];
    const float* ada_w  = (const float*)d_in[12];
    const float* ada_b  = (const float*)d_in[13];
    const float* bias_t = (const float*)d_in[14];

    // workspace layout (bytes)
    char* ws = (char*)d_ws;
    unsigned short* h_buf   = (unsigned short*)ws;               // 25,165,824
    unsigned short* big_buf = (unsigned short*)(ws + 25165824);  // 100,663,296 (qkv & ff1 share)
    unsigned short* wqkv    = (unsigned short*)(ws + 125829120); // 1,769,472
    unsigned short* wproj   = (unsigned short*)(ws + 127598592); // 589,824
    unsigned short* wff1    = (unsigned short*)(ws + 128188416); // 2,359,296
    unsigned short* wff2    = (unsigned short*)(ws + 130547712); // 2,359,296
    float*          ada_out = (float*)(ws + 132907008);          // 147,456
    float*          se      = (float*)(ws + 133054464);          // 12,288

    float* x_acc = (float*)d_out;  // residual stream accumulated in f32 directly in d_out

    const int NEL = 8 * 4096 * 384;  // 12,582,912
    const int M = 32768;

    x_init_kernel<<<(NEL + 255) / 256, 256, 0, stream>>>(x_in, x_acc, NEL);

    // weight conversions f32 -> bf16 (both layers at once)
    f2bf_kernel<<<(884736 + 255) / 256, 256, 0, stream>>>(qkv_w, wqkv, 884736);
    f2bf_kernel<<<(294912 + 255) / 256, 256, 0, stream>>>(proj_w, wproj, 294912);
    f2bf_kernel<<<(1179648 + 255) / 256, 256, 0, stream>>>(ff1_w, wff1, 1179648);
    f2bf_kernel<<<(1179648 + 255) / 256, 256, 0, stream>>>(ff2_w, wff2, 1179648);

    silu_kernel<<<(3072 + 255) / 256, 256, 0, stream>>>(emb, se, 3072);
    ada_kernel<<<dim3(2304, 2), 64, 0, stream>>>(se, ada_w, ada_b, ada_out);

    for (int layer = 0; layer < 2; layer++) {
        const int shift = layer ? 4 : 0;
        const float* ada_l = ada_out + (long)layer * 8 * 2304;
        // splits: sh_sa 0, sc_sa 384, g_sa 768, sh_ff 1152, sc_ff 1536, g_ff 1920

        ln_mod_kernel<<<M, 64, 0, stream>>>(x_acc, ada_l, h_buf, 0, 384);

        gemm128<EPI_STORE, true><<<dim3(9, 256), 256, 0, stream>>>(
            h_buf, wqkv + (long)layer * 1152 * 384, qkv_b + layer * 1152,
            big_buf, nullptr, nullptr, M, 1152, 384, shift);

        attn_kernel<<<dim3(12, 512), 64, 0, stream>>>(
            big_buf, bias_t + layer * 225 * 12, h_buf, shift);

        gemm128<EPI_RES_WIN, false><<<dim3(3, 256), 256, 0, stream>>>(
            h_buf, wproj + (long)layer * 384 * 384, proj_b + layer * 384,
            nullptr, x_acc, ada_l + 768, M, 384, 384, shift);

        ln_mod_kernel<<<M, 64, 0, stream>>>(x_acc, ada_l, h_buf, 1152, 1536);

        gemm128<EPI_GELU, false><<<dim3(12, 256), 256, 0, stream>>>(
            h_buf, wff1 + (long)layer * 1536 * 384, ff1_b + layer * 1536,
            big_buf, nullptr, nullptr, M, 1536, 384, 0);

        gemm128<EPI_RES_ID, false><<<dim3(3, 256), 256, 0, stream>>>(
            big_buf, wff2 + (long)layer * 384 * 1536, ff2_b + layer * 384,
            nullptr, x_acc, ada_l + 1920, M, 384, 1536, 0);
    }
}

// Round 3
// 794.813 us; speedup vs baseline: 1.1858x; 1.1858x over previous
//
#include <hip/hip_runtime.h>

typedef __bf16 bf16_t;
typedef bf16_t bf16x8 __attribute__((ext_vector_type(8)));
typedef float f32x4 __attribute__((ext_vector_type(4)));

#define EPI_STORE 0
#define EPI_GELU 1
#define EPI_RES_WIN 2
#define EPI_RES_ID 3

__device__ __forceinline__ float bf2f(unsigned short u) {
    union { unsigned int i; float f; } x; x.i = ((unsigned int)u) << 16; return x.f;
}
__device__ __forceinline__ unsigned short f2bf(float f) {
    union { float f; unsigned int u; } x; x.f = f;
    unsigned int u = x.u;
    return (unsigned short)((u + 0x7fffu + ((u >> 16) & 1u)) >> 16);
}

// async global->LDS 16B: LDS dest is wave-uniform base + lane*16
__device__ __forceinline__ void async_cp16(const unsigned short* g, unsigned short* l) {
    __builtin_amdgcn_global_load_lds(
        (const __attribute__((address_space(1))) unsigned int*)g,
        (__attribute__((address_space(3))) unsigned int*)l, 16, 0, 0);
}

// window-layout row m (0..32767) -> image-layout row (b*4096 + l)
__device__ __forceinline__ int map_win(int m, int shift) {
    int n = m & 63, w = m >> 6;
    int b = w >> 6, ww = w & 63;
    int hh = ((ww >> 3) * 8 + (n >> 3) + shift) & 63;
    int wc = ((ww & 7) * 8 + (n & 7) + shift) & 63;
    return (b << 12) + (hh << 6) + wc;
}

// ---------------- small kernels ----------------

__global__ void f2bf_kernel(const float* __restrict__ in,
                            unsigned short* __restrict__ out, int n) {
    int i = blockIdx.x * 256 + threadIdx.x;
    if (i < n) out[i] = f2bf(in[i]);
}

__global__ void silu_kernel(const float* __restrict__ emb,
                            float* __restrict__ out, int n) {
    int i = blockIdx.x * 256 + threadIdx.x;
    if (i < n) { float e = emb[i]; out[i] = e / (1.0f + expf(-e)); }
}

__global__ __launch_bounds__(64) void ada_kernel(
    const float* __restrict__ se,           // [8][384] silu(emb)
    const float* __restrict__ ada_w,        // [2][2304][384]
    const float* __restrict__ ada_b,        // [2][2304]
    float* __restrict__ ada_out)            // [2][8][2304]
{
    int j = blockIdx.x;
    int layer = blockIdx.y;
    int t = threadIdx.x;
    const float* wr = ada_w + ((long)layer * 2304 + j) * 384;
    float w[6];
#pragma unroll
    for (int q = 0; q < 6; q++) w[q] = wr[t + 64 * q];
    float bias = ada_b[layer * 2304 + j];
    for (int b = 0; b < 8; b++) {
        float p = 0.f;
#pragma unroll
        for (int q = 0; q < 6; q++) p += se[b * 384 + t + 64 * q] * w[q];
#pragma unroll
        for (int o = 32; o > 0; o >>= 1) p += __shfl_xor(p, o);
        if (t == 0) ada_out[((long)layer * 8 + b) * 2304 + j] = p + bias;
    }
}

// LayerNorm + adaLN modulate: h = LN(x)*(1+sc) + sh; one wave per row, 4 rows/block
__global__ __launch_bounds__(256) void ln_mod_kernel(
    const float* __restrict__ x, const float* __restrict__ ada,
    unsigned short* __restrict__ h, int sh_off, int sc_off)
{
    int row = blockIdx.x * 4 + (threadIdx.x >> 6);
    int b = row >> 12;
    int t = threadIdx.x & 63;
    const float* xr = x + (long)row * 384;
    float v[6];
    float s = 0.f;
#pragma unroll
    for (int j = 0; j < 6; j++) { v[j] = xr[t + 64 * j]; s += v[j]; }
#pragma unroll
    for (int o = 32; o > 0; o >>= 1) s += __shfl_xor(s, o);
    float mean = s * (1.0f / 384.0f);
    float s2 = 0.f;
#pragma unroll
    for (int j = 0; j < 6; j++) { float d = v[j] - mean; s2 += d * d; }
#pragma unroll
    for (int o = 32; o > 0; o >>= 1) s2 += __shfl_xor(s2, o);
    float rstd = rsqrtf(s2 * (1.0f / 384.0f) + 1e-6f);
    const float* adab = ada + (long)b * 2304;
#pragma unroll
    for (int j = 0; j < 6; j++) {
        int c = t + 64 * j;
        float val = (v[j] - mean) * rstd * (1.0f + adab[sc_off + c]) + adab[sh_off + c];
        h[(long)row * 384 + c] = f2bf(val);
    }
}

// ---------------- GEMM: out[M,N] = A[M,K] @ W[N,K]^T + bias ----------------
// 128x128 tile, BK=32, 256 threads = 4 waves; global_load_lds width-16 staging.

template <int EPI, bool GATHER, bool RESINIT>
__global__ __launch_bounds__(256) void gemm128(
    const unsigned short* __restrict__ A,
    const unsigned short* __restrict__ W,
    const float* __restrict__ bias,
    unsigned short* __restrict__ out,
    float* __restrict__ xres,
    const float* __restrict__ xbase,
    const float* __restrict__ gvec,
    int M, int N, int K, int shift)
{
    __shared__ __align__(16) unsigned short As[128 * 32];
    __shared__ __align__(16) unsigned short Bs[128 * 32];

    const int tid = threadIdx.x;
    const int wv = tid >> 6, lane = tid & 63;
    const int m0 = blockIdx.y * 128, n0 = blockIdx.x * 128;

    // staging: wave wv covers rows [wv*32, wv*32+32) in two 16-row chunks
    const int srow = wv * 32 + (lane >> 2);
    const int scol = (lane & 3) * 8;
    const long asrc0 = GATHER ? (long)map_win(m0 + srow, shift) : (long)(m0 + srow);
    const long asrc1 = GATHER ? (long)map_win(m0 + srow + 16, shift) : (long)(m0 + srow + 16);
    const unsigned short* ag0 = A + asrc0 * K + scol;
    const unsigned short* ag1 = A + asrc1 * K + scol;
    const unsigned short* bg0 = W + (long)(n0 + srow) * K + scol;
    const unsigned short* bg1 = W + (long)(n0 + srow + 16) * K + scol;
    unsigned short* al0 = As + wv * 1024;
    unsigned short* al1 = As + wv * 1024 + 512;
    unsigned short* bl0 = Bs + wv * 1024;
    unsigned short* bl1 = Bs + wv * 1024 + 512;

    const int wm = (wv >> 1) * 64, wn = (wv & 1) * 64;
    const int l16 = lane & 15, quad = lane >> 4;

    f32x4 acc[4][4] = {};

    for (int k0 = 0; k0 < K; k0 += 32) {
        async_cp16(ag0 + k0, al0);
        async_cp16(ag1 + k0, al1);
        async_cp16(bg0 + k0, bl0);
        async_cp16(bg1 + k0, bl1);
        __syncthreads();

        bf16x8 af[4], bfr[4];
#pragma unroll
        for (int i = 0; i < 4; i++)
            af[i] = *(const bf16x8*)&As[(wm + i * 16 + l16) * 32 + quad * 8];
#pragma unroll
        for (int i = 0; i < 4; i++)
            bfr[i] = *(const bf16x8*)&Bs[(wn + i * 16 + l16) * 32 + quad * 8];
#pragma unroll
        for (int i = 0; i < 4; i++)
#pragma unroll
            for (int j = 0; j < 4; j++)
                acc[i][j] = __builtin_amdgcn_mfma_f32_16x16x32_bf16(af[i], bfr[j], acc[i][j], 0, 0, 0);
        __syncthreads();
    }

#pragma unroll
    for (int i = 0; i < 4; i++) {
#pragma unroll
        for (int j = 0; j < 4; j++) {
            int col = n0 + wn + j * 16 + l16;
            float bv = bias[col];
#pragma unroll
            for (int r = 0; r < 4; r++) {
                int row = m0 + wm + i * 16 + quad * 4 + r;
                float v = acc[i][j][r] + bv;
                if constexpr (EPI == EPI_STORE) {
                    out[(long)row * N + col] = f2bf(v);
                } else if constexpr (EPI == EPI_GELU) {
                    v = 0.5f * v * (1.0f + erff(v * 0.70710678118f));
                    out[(long)row * N + col] = f2bf(v);
                } else {
                    long dst = (EPI == EPI_RES_WIN) ? (long)map_win(row, shift) : (long)row;
                    int b = (int)(dst >> 12);
                    float g = gvec[(long)b * 2304 + col];
                    if constexpr (RESINIT)
                        xres[dst * 384 + col] = xbase[dst * 384 + col] + g * v;
                    else
                        xres[dst * 384 + col] += g * v;
                }
            }
        }
    }
}

// ---------------- MFMA attention: one wave per (window, head), 4 heads/block ----

__device__ __forceinline__ int reg3(int p) { return (p < 56) ? 0 : ((p < 60) ? 1 : 2); }

__global__ __launch_bounds__(256) void attn_kernel(
    const unsigned short* __restrict__ qkv,        // [32768][1152] window layout, bf16
    const float* __restrict__ bias_table,          // layer base [225][12], f32
    unsigned short* __restrict__ out,              // [32768][384] window layout, bf16
    int shift)
{
    __shared__ unsigned short Pl[4][64 * 68];   // P matrix, padded stride 68
    __shared__ unsigned short VTl[4][32 * 68];  // V^T, padded stride 68

    const int wv = threadIdx.x >> 6, lane = threadIdx.x & 63;
    const int head = blockIdx.x * 4 + wv;    // grid.x = 3
    const int win = blockIdx.y;              // 0..511
    const int l16 = lane & 15, quad = lane >> 4;

    unsigned short* P = Pl[wv];
    unsigned short* vt = VTl[wv];

    const long base = (long)win * 64 * 1152 + head * 32;

    // Q,K fragments direct from global: frag i = rows 16i..16i+15, lane(l16,quad)
    // holds row 16i+l16, elems quad*8..+7 (A-layout; B-layout of K^T is identical)
    bf16x8 qf[4], kf[4];
#pragma unroll
    for (int i = 0; i < 4; i++) {
        qf[i] = *(const bf16x8*)&qkv[base + (long)(i * 16 + l16) * 1152 + quad * 8];
        kf[i] = *(const bf16x8*)&qkv[base + 384 + (long)(i * 16 + l16) * 1152 + quad * 8];
    }
    // stage V transposed: lane loads V row `lane` (32 bf16), writes VT[c][lane]
    {
        const uint4* vp = (const uint4*)&qkv[base + 768 + (long)lane * 1152];
#pragma unroll
        for (int c4 = 0; c4 < 4; c4++) {
            uint4 v = vp[c4];
            unsigned int u[4] = {v.x, v.y, v.z, v.w};
#pragma unroll
            for (int e = 0; e < 4; e++) {
                vt[(c4 * 8 + e * 2) * 68 + lane]     = (unsigned short)(u[e] & 0xffffu);
                vt[(c4 * 8 + e * 2 + 1) * 68 + lane] = (unsigned short)(u[e] >> 16);
            }
        }
    }

    // S = Q @ K^T  (4x4 tiles of 16x16, K=32 in one MFMA)
    f32x4 sacc[4][4] = {};
#pragma unroll
    for (int i = 0; i < 4; i++)
#pragma unroll
        for (int j = 0; j < 4; j++)
            sacc[i][j] = __builtin_amdgcn_mfma_f32_16x16x32_bf16(qf[i], kf[j], sacc[i][j], 0, 0, 0);

    const float scale = 0.17677669529663687f;  // 1/sqrt(32)
    const int ww = win & 63, wi = ww >> 3, wj = ww & 7;

    // softmax per query row; C/D layout: row = 16i + quad*4 + r, col = 16j + l16
#pragma unroll
    for (int i = 0; i < 4; i++) {
#pragma unroll
        for (int r = 0; r < 4; r++) {
            int n = i * 16 + quad * 4 + r;
            int nr = n >> 3, nc = n & 7;
            int labq = (shift > 0) ? reg3(wi * 8 + nr) * 3 + reg3(wj * 8 + nc) : 0;
            float v[4];
#pragma unroll
            for (int j = 0; j < 4; j++) {
                int m = j * 16 + l16;
                int mr = m >> 3, mc = m & 7;
                float s = sacc[i][j][r] * scale +
                          bias_table[((nr - mr + 7) * 15 + (nc - mc + 7)) * 12 + head];
                if (shift > 0) {
                    int labm = reg3(wi * 8 + mr) * 3 + reg3(wj * 8 + mc);
                    if (labm != labq) s -= 100.0f;
                }
                v[j] = s;
            }
            float mx = fmaxf(fmaxf(v[0], v[1]), fmaxf(v[2], v[3]));
#pragma unroll
            for (int o = 1; o < 16; o <<= 1) mx = fmaxf(mx, __shfl_xor(mx, o));
            float sum = 0.f;
#pragma unroll
            for (int j = 0; j < 4; j++) { v[j] = __expf(v[j] - mx); sum += v[j]; }
#pragma unroll
            for (int o = 1; o < 16; o <<= 1) sum += __shfl_xor(sum, o);
            float inv = 1.0f / sum;
#pragma unroll
            for (int j = 0; j < 4; j++)
                P[n * 68 + j * 16 + l16] = f2bf(v[j] * inv);
        }
    }
    __syncthreads();  // order LDS writes (P, VT) before fragment reads

    // O = P @ V : A-frags from P LDS, B-frags from V^T LDS
    f32x4 oacc[4][2] = {};
#pragma unroll
    for (int kt = 0; kt < 2; kt++) {
        bf16x8 pf[4], vf[2];
#pragma unroll
        for (int i = 0; i < 4; i++)
            pf[i] = *(const bf16x8*)&P[(i * 16 + l16) * 68 + kt * 32 + quad * 8];
#pragma unroll
        for (int jt = 0; jt < 2; jt++)
            vf[jt] = *(const bf16x8*)&vt[(jt * 16 + l16) * 68 + kt * 32 + quad * 8];
#pragma unroll
        for (int i = 0; i < 4; i++)
#pragma unroll
            for (int jt = 0; jt < 2; jt++)
                oacc[i][jt] = __builtin_amdgcn_mfma_f32_16x16x32_bf16(pf[i], vf[jt], oacc[i][jt], 0, 0, 0);
    }

#pragma unroll
    for (int i = 0; i < 4; i++)
#pragma unroll
        for (int jt = 0; jt < 2; jt++)
#pragma unroll
            for (int r = 0; r < 4; r++) {
                int row = i * 16 + quad * 4 + r;
                int col = jt * 16 + l16;
                out[((long)win * 64 + row) * 384 + head * 32 + col] = f2bf(oacc[i][jt][r]);
            }
}

// ---------------- launch ----------------

extern "C" void kernel_launch(void* const* d_in, const int* in_sizes, int n_in,
                              void* d_out, int out_size, void* d_ws, size_t ws_size,
                              hipStream_t stream) {
    const float* x_in   = (const float*)d_in[0];
    const float* emb    = (const float*)d_in[3];
    const float* qkv_w  = (const float*)d_in[4];
    const float* qkv_b  = (const float*)d_in[5];
    const float* proj_w = (const float*)d_in[6];
    const float* proj_b = (const float*)d_in[7];
    const float* ff1_w  = (const float*)d_in[8];
    const float* ff1_b  = (const float*)d_in[9];
    const float* ff2_w  = (const float*)d_in[10];
    const float* ff2_b  = (const float*)d_in[11];
    const float* ada_w  = (const float*)d_in[12];
    const float* ada_b  = (const float*)d_in[13];
    const float* bias_t = (const float*)d_in[14];

    char* ws = (char*)d_ws;
    unsigned short* h_buf   = (unsigned short*)ws;               // 25,165,824
    unsigned short* big_buf = (unsigned short*)(ws + 25165824);  // 100,663,296 (qkv & ff1 share)
    unsigned short* wqkv    = (unsigned short*)(ws + 125829120); // 1,769,472
    unsigned short* wproj   = (unsigned short*)(ws + 127598592); // 589,824
    unsigned short* wff1    = (unsigned short*)(ws + 128188416); // 2,359,296
    unsigned short* wff2    = (unsigned short*)(ws + 130547712); // 2,359,296
    float*          ada_out = (float*)(ws + 132907008);          // 147,456
    float*          se      = (float*)(ws + 133054464);          // 12,288

    float* x_acc = (float*)d_out;  // f32 residual stream lives in d_out

    const int M = 32768;

    // weight conversions f32 -> bf16 (both layers)
    f2bf_kernel<<<(884736 + 255) / 256, 256, 0, stream>>>(qkv_w, wqkv, 884736);
    f2bf_kernel<<<(294912 + 255) / 256, 256, 0, stream>>>(proj_w, wproj, 294912);
    f2bf_kernel<<<(1179648 + 255) / 256, 256, 0, stream>>>(ff1_w, wff1, 1179648);
    f2bf_kernel<<<(1179648 + 255) / 256, 256, 0, stream>>>(ff2_w, wff2, 1179648);

    silu_kernel<<<(3072 + 255) / 256, 256, 0, stream>>>(emb, se, 3072);
    ada_kernel<<<dim3(2304, 2), 64, 0, stream>>>(se, ada_w, ada_b, ada_out);

    for (int layer = 0; layer < 2; layer++) {
        const int shift = layer ? 4 : 0;
        const float* ada_l = ada_out + (long)layer * 8 * 2304;
        // splits: sh_sa 0, sc_sa 384, g_sa 768, sh_ff 1152, sc_ff 1536, g_ff 1920

        // layer 0 LN reads x_in directly (x_acc not yet initialized)
        ln_mod_kernel<<<M / 4, 256, 0, stream>>>(layer == 0 ? x_in : x_acc,
                                                 ada_l, h_buf, 0, 384);

        gemm128<EPI_STORE, true, false><<<dim3(9, 256), 256, 0, stream>>>(
            h_buf, wqkv + (long)layer * 1152 * 384, qkv_b + layer * 1152,
            big_buf, nullptr, nullptr, nullptr, M, 1152, 384, shift);

        attn_kernel<<<dim3(3, 512), 256, 0, stream>>>(
            big_buf, bias_t + layer * 225 * 12, h_buf, shift);

        if (layer == 0) {
            gemm128<EPI_RES_WIN, false, true><<<dim3(3, 256), 256, 0, stream>>>(
                h_buf, wproj, proj_b,
                nullptr, x_acc, x_in, ada_l + 768, M, 384, 384, shift);
        } else {
            gemm128<EPI_RES_WIN, false, false><<<dim3(3, 256), 256, 0, stream>>>(
                h_buf, wproj + (long)384 * 384, proj_b + 384,
                nullptr, x_acc, nullptr, ada_l + 768, M, 384, 384, shift);
        }

        ln_mod_kernel<<<M / 4, 256, 0, stream>>>(x_acc, ada_l, h_buf, 1152, 1536);

        gemm128<EPI_GELU, false, false><<<dim3(12, 256), 256, 0, stream>>>(
            h_buf, wff1 + (long)layer * 1536 * 384, ff1_b + layer * 1536,
            big_buf, nullptr, nullptr, nullptr, M, 1536, 384, 0);

        gemm128<EPI_RES_ID, false, false><<<dim3(3, 256), 256, 0, stream>>>(
            big_buf, wff2 + (long)layer * 384 * 1536, ff2_b + layer * 384,
            nullptr, x_acc, nullptr, ada_l + 1920, M, 384, 1536, 0);
    }
}

// Round 4
// 771.745 us; speedup vs baseline: 1.2213x; 1.0299x over previous
//
#include <hip/hip_runtime.h>

typedef __bf16 bf16_t;
typedef bf16_t bf16x8 __attribute__((ext_vector_type(8)));
typedef float f32x4 __attribute__((ext_vector_type(4)));

#define EPI_STORE 0
#define EPI_GELU 1
#define EPI_RES_WIN 2
#define EPI_RES_ID 3

__device__ __forceinline__ float bf2f(unsigned short u) {
    union { unsigned int i; float f; } x; x.i = ((unsigned int)u) << 16; return x.f;
}
__device__ __forceinline__ unsigned short f2bf(float f) {
    union { __bf16 h; unsigned short u; } c; c.h = (__bf16)f; return c.u;
}
__device__ __forceinline__ float gelu_f(float v) {
    // tanh-form GELU: 0.5v(1+tanh(u)) = v * sigmoid(2u)
    float u = v * (0.7978845608f + 0.0356774081f * v * v);
    return v / (1.0f + __expf(-2.0f * u));
}

// async global->LDS 16B: LDS dest is wave-uniform base + lane*16
__device__ __forceinline__ void async_cp16(const unsigned short* g, unsigned short* l) {
    __builtin_amdgcn_global_load_lds(
        (const __attribute__((address_space(1))) unsigned int*)g,
        (__attribute__((address_space(3))) unsigned int*)l, 16, 0, 0);
}

// window-layout row m (0..32767) -> image-layout row (b*4096 + l)
__device__ __forceinline__ int map_win(int m, int shift) {
    int n = m & 63, w = m >> 6;
    int b = w >> 6, ww = w & 63;
    int hh = ((ww >> 3) * 8 + (n >> 3) + shift) & 63;
    int wc = ((ww & 7) * 8 + (n & 7) + shift) & 63;
    return (b << 12) + (hh << 6) + wc;
}

// ---------------- small kernels ----------------

__global__ void f2bf_kernel(const float* __restrict__ in,
                            unsigned short* __restrict__ out, int n) {
    int i = blockIdx.x * 256 + threadIdx.x;
    if (i < n) out[i] = f2bf(in[i]);
}

__global__ void silu_kernel(const float* __restrict__ emb,
                            float* __restrict__ out, int n) {
    int i = blockIdx.x * 256 + threadIdx.x;
    if (i < n) { float e = emb[i]; out[i] = e / (1.0f + expf(-e)); }
}

__global__ __launch_bounds__(64) void ada_kernel(
    const float* __restrict__ se,           // [8][384] silu(emb)
    const float* __restrict__ ada_w,        // [2][2304][384]
    const float* __restrict__ ada_b,        // [2][2304]
    float* __restrict__ ada_out)            // [2][8][2304]
{
    int j = blockIdx.x;
    int layer = blockIdx.y;
    int t = threadIdx.x;
    const float* wr = ada_w + ((long)layer * 2304 + j) * 384;
    float w[6];
#pragma unroll
    for (int q = 0; q < 6; q++) w[q] = wr[t + 64 * q];
    float bias = ada_b[layer * 2304 + j];
    for (int b = 0; b < 8; b++) {
        float p = 0.f;
#pragma unroll
        for (int q = 0; q < 6; q++) p += se[b * 384 + t + 64 * q] * w[q];
#pragma unroll
        for (int o = 32; o > 0; o >>= 1) p += __shfl_xor(p, o);
        if (t == 0) ada_out[((long)layer * 8 + b) * 2304 + j] = p + bias;
    }
}

// LayerNorm + adaLN modulate: h = LN(x)*(1+sc) + sh; one wave per row, 4 rows/block
__global__ __launch_bounds__(256) void ln_mod_kernel(
    const float* __restrict__ x, const float* __restrict__ ada,
    unsigned short* __restrict__ h, int sh_off, int sc_off)
{
    int row = blockIdx.x * 4 + (threadIdx.x >> 6);
    int b = row >> 12;
    int t = threadIdx.x & 63;
    const float* xr = x + (long)row * 384;
    float v[6];
    float s = 0.f;
#pragma unroll
    for (int j = 0; j < 6; j++) { v[j] = xr[t + 64 * j]; s += v[j]; }
#pragma unroll
    for (int o = 32; o > 0; o >>= 1) s += __shfl_xor(s, o);
    float mean = s * (1.0f / 384.0f);
    float s2 = 0.f;
#pragma unroll
    for (int j = 0; j < 6; j++) { float d = v[j] - mean; s2 += d * d; }
#pragma unroll
    for (int o = 32; o > 0; o >>= 1) s2 += __shfl_xor(s2, o);
    float rstd = rsqrtf(s2 * (1.0f / 384.0f) + 1e-6f);
    const float* adab = ada + (long)b * 2304;
#pragma unroll
    for (int j = 0; j < 6; j++) {
        int c = t + 64 * j;
        float val = (v[j] - mean) * rstd * (1.0f + adab[sc_off + c]) + adab[sh_off + c];
        h[(long)row * 384 + c] = f2bf(val);
    }
}

// ---------------- GEMM: out[M,N] = A[M,K] @ W[N,K]^T + bias ----------------
// 128x128 tile, BK=64, 256 threads = 4 waves; global_load_lds width-16 staging
// with XOR K-chunk swizzle (chunk ^= row&7) for conflict-free ds_read_b128.

template <int EPI, bool GATHER, bool RESINIT>
__global__ __launch_bounds__(256) void gemm128(
    const unsigned short* __restrict__ A,
    const unsigned short* __restrict__ W,
    const float* __restrict__ bias,
    unsigned short* __restrict__ out,
    float* __restrict__ xres,
    const float* __restrict__ xbase,
    const float* __restrict__ gvec,
    int M, int N, int K, int shift)
{
    __shared__ __align__(16) unsigned short As[128 * 64];
    __shared__ __align__(16) unsigned short Bs[128 * 64];

    const int tid = threadIdx.x;
    const int wv = tid >> 6, lane = tid & 63;
    const int m0 = blockIdx.y * 128, n0 = blockIdx.x * 128;

    // staging: lane -> (r8 = lane>>3, c = lane&7); stores global chunk c^r8 so
    // that LDS slot (row, pc) holds global chunk pc ^ (row&7).
    const int r8 = lane >> 3;
    const int cofs = ((lane & 7) ^ r8) * 8;
    long arow[4], brow[4];
#pragma unroll
    for (int t = 0; t < 4; t++) {
        int rl = wv * 32 + t * 8 + r8;
        arow[t] = GATHER ? (long)map_win(m0 + rl, shift) : (long)(m0 + rl);
        brow[t] = (long)(n0 + rl);
    }

    const int wm = (wv >> 1) * 64, wn = (wv & 1) * 64;
    const int l16 = lane & 15, quad = lane >> 4;
    const int swz = l16 & 7;

    f32x4 acc[4][4] = {};

    for (int k0 = 0; k0 < K; k0 += 64) {
#pragma unroll
        for (int t = 0; t < 4; t++) {
            async_cp16(A + arow[t] * K + k0 + cofs, As + (wv * 32 + t * 8) * 64);
            async_cp16(W + brow[t] * K + k0 + cofs, Bs + (wv * 32 + t * 8) * 64);
        }
        __syncthreads();

#pragma unroll
        for (int kk = 0; kk < 2; kk++) {
            bf16x8 af[4], bfr[4];
#pragma unroll
            for (int i = 0; i < 4; i++)
                af[i] = *(const bf16x8*)&As[(wm + i * 16 + l16) * 64 +
                                            (((kk * 4 + quad) ^ swz) * 8)];
#pragma unroll
            for (int j = 0; j < 4; j++)
                bfr[j] = *(const bf16x8*)&Bs[(wn + j * 16 + l16) * 64 +
                                             (((kk * 4 + quad) ^ swz) * 8)];
#pragma unroll
            for (int i = 0; i < 4; i++)
#pragma unroll
                for (int j = 0; j < 4; j++)
                    acc[i][j] = __builtin_amdgcn_mfma_f32_16x16x32_bf16(af[i], bfr[j], acc[i][j], 0, 0, 0);
        }
        __syncthreads();
    }

    float bv[4];
#pragma unroll
    for (int j = 0; j < 4; j++) bv[j] = bias[n0 + wn + j * 16 + l16];

#pragma unroll
    for (int i = 0; i < 4; i++) {
#pragma unroll
        for (int r = 0; r < 4; r++) {
            int row = m0 + wm + i * 16 + quad * 4 + r;
            if constexpr (EPI == EPI_STORE || EPI == EPI_GELU) {
                unsigned short* orow = out + (long)row * N + n0 + wn + l16;
#pragma unroll
                for (int j = 0; j < 4; j++) {
                    float v = acc[i][j][r] + bv[j];
                    if constexpr (EPI == EPI_GELU) v = gelu_f(v);
                    orow[j * 16] = f2bf(v);
                }
            } else {
                long dst = (EPI == EPI_RES_WIN) ? (long)map_win(row, shift) : (long)row;
                int b = (int)(dst >> 12);
                float* xrow = xres + dst * 384 + n0 + wn + l16;
                const float* grow = gvec + (long)b * 2304 + n0 + wn + l16;
#pragma unroll
                for (int j = 0; j < 4; j++) {
                    float v = acc[i][j][r] + bv[j];
                    if constexpr (RESINIT) {
                        const float* xbrow = xbase + dst * 384 + n0 + wn + l16;
                        xrow[j * 16] = xbrow[j * 16] + grow[j * 16] * v;
                    } else {
                        xrow[j * 16] += grow[j * 16] * v;
                    }
                }
            }
        }
    }
}

// ---------------- MFMA attention: one wave per (window, head), 4 heads/block ----

__device__ __forceinline__ int reg3(int p) { return (p < 56) ? 0 : ((p < 60) ? 1 : 2); }

__global__ __launch_bounds__(256) void attn_kernel(
    const unsigned short* __restrict__ qkv,        // [32768][1152] window layout, bf16
    const float* __restrict__ bias_table,          // layer base [225][12], f32
    unsigned short* __restrict__ out,              // [32768][384] window layout, bf16
    int shift)
{
    __shared__ unsigned short Pl[4][64 * 68];   // P matrix, padded stride 68
    __shared__ unsigned short VTl[4][32 * 68];  // V^T, padded stride 68

    const int wv = threadIdx.x >> 6, lane = threadIdx.x & 63;
    const int head = blockIdx.x * 4 + wv;    // grid.x = 3
    const int win = blockIdx.y;              // 0..511
    const int l16 = lane & 15, quad = lane >> 4;

    unsigned short* P = Pl[wv];
    unsigned short* vt = VTl[wv];

    const long base = (long)win * 64 * 1152 + head * 32;

    bf16x8 qf[4], kf[4];
#pragma unroll
    for (int i = 0; i < 4; i++) {
        qf[i] = *(const bf16x8*)&qkv[base + (long)(i * 16 + l16) * 1152 + quad * 8];
        kf[i] = *(const bf16x8*)&qkv[base + 384 + (long)(i * 16 + l16) * 1152 + quad * 8];
    }
    {
        const uint4* vp = (const uint4*)&qkv[base + 768 + (long)lane * 1152];
#pragma unroll
        for (int c4 = 0; c4 < 4; c4++) {
            uint4 v = vp[c4];
            unsigned int u[4] = {v.x, v.y, v.z, v.w};
#pragma unroll
            for (int e = 0; e < 4; e++) {
                vt[(c4 * 8 + e * 2) * 68 + lane]     = (unsigned short)(u[e] & 0xffffu);
                vt[(c4 * 8 + e * 2 + 1) * 68 + lane] = (unsigned short)(u[e] >> 16);
            }
        }
    }

    // S = Q @ K^T
    f32x4 sacc[4][4] = {};
#pragma unroll
    for (int i = 0; i < 4; i++)
#pragma unroll
        for (int j = 0; j < 4; j++)
            sacc[i][j] = __builtin_amdgcn_mfma_f32_16x16x32_bf16(qf[i], kf[j], sacc[i][j], 0, 0, 0);

    const float scale = 0.17677669529663687f;  // 1/sqrt(32)
    const int ww = win & 63, wi = ww >> 3, wj = ww & 7;

#pragma unroll
    for (int i = 0; i < 4; i++) {
#pragma unroll
        for (int r = 0; r < 4; r++) {
            int n = i * 16 + quad * 4 + r;
            int nr = n >> 3, nc = n & 7;
            int labq = (shift > 0) ? reg3(wi * 8 + nr) * 3 + reg3(wj * 8 + nc) : 0;
            float v[4];
#pragma unroll
            for (int j = 0; j < 4; j++) {
                int m = j * 16 + l16;
                int mr = m >> 3, mc = m & 7;
                float s = sacc[i][j][r] * scale +
                          bias_table[((nr - mr + 7) * 15 + (nc - mc + 7)) * 12 + head];
                if (shift > 0) {
                    int labm = reg3(wi * 8 + mr) * 3 + reg3(wj * 8 + mc);
                    if (labm != labq) s -= 100.0f;
                }
                v[j] = s;
            }
            float mx = fmaxf(fmaxf(v[0], v[1]), fmaxf(v[2], v[3]));
#pragma unroll
            for (int o = 1; o < 16; o <<= 1) mx = fmaxf(mx, __shfl_xor(mx, o));
            float sum = 0.f;
#pragma unroll
            for (int j = 0; j < 4; j++) { v[j] = __expf(v[j] - mx); sum += v[j]; }
#pragma unroll
            for (int o = 1; o < 16; o <<= 1) sum += __shfl_xor(sum, o);
            float inv = 1.0f / sum;
#pragma unroll
            for (int j = 0; j < 4; j++)
                P[n * 68 + j * 16 + l16] = f2bf(v[j] * inv);
        }
    }
    __syncthreads();

    // O = P @ V
    f32x4 oacc[4][2] = {};
#pragma unroll
    for (int kt = 0; kt < 2; kt++) {
        bf16x8 pf[4], vf[2];
#pragma unroll
        for (int i = 0; i < 4; i++)
            pf[i] = *(const bf16x8*)&P[(i * 16 + l16) * 68 + kt * 32 + quad * 8];
#pragma unroll
        for (int jt = 0; jt < 2; jt++)
            vf[jt] = *(const bf16x8*)&vt[(jt * 16 + l16) * 68 + kt * 32 + quad * 8];
#pragma unroll
        for (int i = 0; i < 4; i++)
#pragma unroll
            for (int jt = 0; jt < 2; jt++)
                oacc[i][jt] = __builtin_amdgcn_mfma_f32_16x16x32_bf16(pf[i], vf[jt], oacc[i][jt], 0, 0, 0);
    }

#pragma unroll
    for (int i = 0; i < 4; i++)
#pragma unroll
        for (int jt = 0; jt < 2; jt++)
#pragma unroll
            for (int r = 0; r < 4; r++) {
                int row = i * 16 + quad * 4 + r;
                int col = jt * 16 + l16;
                out[((long)win * 64 + row) * 384 + head * 32 + col] = f2bf(oacc[i][jt][r]);
            }
}

// ---------------- launch ----------------

extern "C" void kernel_launch(void* const* d_in, const int* in_sizes, int n_in,
                              void* d_out, int out_size, void* d_ws, size_t ws_size,
                              hipStream_t stream) {
    const float* x_in   = (const float*)d_in[0];
    const float* emb    = (const float*)d_in[3];
    const float* qkv_w  = (const float*)d_in[4];
    const float* qkv_b  = (const float*)d_in[5];
    const float* proj_w = (const float*)d_in[6];
    const float* proj_b = (const float*)d_in[7];
    const float* ff1_w  = (const float*)d_in[8];
    const float* ff1_b  = (const float*)d_in[9];
    const float* ff2_w  = (const float*)d_in[10];
    const float* ff2_b  = (const float*)d_in[11];
    const float* ada_w  = (const float*)d_in[12];
    const float* ada_b  = (const float*)d_in[13];
    const float* bias_t = (const float*)d_in[14];

    char* ws = (char*)d_ws;
    unsigned short* h_buf   = (unsigned short*)ws;               // 25,165,824
    unsigned short* big_buf = (unsigned short*)(ws + 25165824);  // 100,663,296 (qkv & ff1 share)
    unsigned short* wqkv    = (unsigned short*)(ws + 125829120); // 1,769,472
    unsigned short* wproj   = (unsigned short*)(ws + 127598592); // 589,824
    unsigned short* wff1    = (unsigned short*)(ws + 128188416); // 2,359,296
    unsigned short* wff2    = (unsigned short*)(ws + 130547712); // 2,359,296
    float*          ada_out = (float*)(ws + 132907008);          // 147,456
    float*          se      = (float*)(ws + 133054464);          // 12,288

    float* x_acc = (float*)d_out;  // f32 residual stream lives in d_out

    const int M = 32768;

    f2bf_kernel<<<(884736 + 255) / 256, 256, 0, stream>>>(qkv_w, wqkv, 884736);
    f2bf_kernel<<<(294912 + 255) / 256, 256, 0, stream>>>(proj_w, wproj, 294912);
    f2bf_kernel<<<(1179648 + 255) / 256, 256, 0, stream>>>(ff1_w, wff1, 1179648);
    f2bf_kernel<<<(1179648 + 255) / 256, 256, 0, stream>>>(ff2_w, wff2, 1179648);

    silu_kernel<<<(3072 + 255) / 256, 256, 0, stream>>>(emb, se, 3072);
    ada_kernel<<<dim3(2304, 2), 64, 0, stream>>>(se, ada_w, ada_b, ada_out);

    for (int layer = 0; layer < 2; layer++) {
        const int shift = layer ? 4 : 0;
        const float* ada_l = ada_out + (long)layer * 8 * 2304;
        // splits: sh_sa 0, sc_sa 384, g_sa 768, sh_ff 1152, sc_ff 1536, g_ff 1920

        ln_mod_kernel<<<M / 4, 256, 0, stream>>>(layer == 0 ? x_in : x_acc,
                                                 ada_l, h_buf, 0, 384);

        gemm128<EPI_STORE, true, false><<<dim3(9, 256), 256, 0, stream>>>(
            h_buf, wqkv + (long)layer * 1152 * 384, qkv_b + layer * 1152,
            big_buf, nullptr, nullptr, nullptr, M, 1152, 384, shift);

        attn_kernel<<<dim3(3, 512), 256, 0, stream>>>(
            big_buf, bias_t + layer * 225 * 12, h_buf, shift);

        if (layer == 0) {
            gemm128<EPI_RES_WIN, false, true><<<dim3(3, 256), 256, 0, stream>>>(
                h_buf, wproj, proj_b,
                nullptr, x_acc, x_in, ada_l + 768, M, 384, 384, shift);
        } else {
            gemm128<EPI_RES_WIN, false, false><<<dim3(3, 256), 256, 0, stream>>>(
                h_buf, wproj + (long)384 * 384, proj_b + 384,
                nullptr, x_acc, nullptr, ada_l + 768, M, 384, 384, shift);
        }

        ln_mod_kernel<<<M / 4, 256, 0, stream>>>(x_acc, ada_l, h_buf, 1152, 1536);

        gemm128<EPI_GELU, false, false><<<dim3(12, 256), 256, 0, stream>>>(
            h_buf, wff1 + (long)layer * 1536 * 384, ff1_b + layer * 1536,
            big_buf, nullptr, nullptr, nullptr, M, 1536, 384, 0);

        gemm128<EPI_RES_ID, false, false><<<dim3(3, 256), 256, 0, stream>>>(
            big_buf, wff2 + (long)layer * 384 * 1536, ff2_b + layer * 384,
            nullptr, x_acc, nullptr, ada_l + 1920, M, 384, 1536, 0);
    }
}

// Round 5
// 686.925 us; speedup vs baseline: 1.3721x; 1.1235x over previous
//
#include <hip/hip_runtime.h>

typedef __bf16 bf16_t;
typedef bf16_t bf16x8 __attribute__((ext_vector_type(8)));
typedef float f32x4 __attribute__((ext_vector_type(4)));

#define EPI_STORE 0
#define EPI_GELU 1
#define EPI_RES_WIN 2
#define EPI_RES_ID 3

__device__ __forceinline__ float bf2f(unsigned short u) {
    union { unsigned int i; float f; } x; x.i = ((unsigned int)u) << 16; return x.f;
}
__device__ __forceinline__ unsigned short f2bf(float f) {
    union { __bf16 h; unsigned short u; } c; c.h = (__bf16)f; return c.u;
}
__device__ __forceinline__ float gelu_f(float v) {
    float u = v * (0.7978845608f + 0.0356774081f * v * v);
    return v / (1.0f + __expf(-2.0f * u));
}

// async global->LDS 16B: LDS dest is wave-uniform base + lane*16
__device__ __forceinline__ void async_cp16(const unsigned short* g, unsigned short* l) {
    __builtin_amdgcn_global_load_lds(
        (const __attribute__((address_space(1))) unsigned int*)g,
        (__attribute__((address_space(3))) unsigned int*)l, 16, 0, 0);
}

// window-layout row m (0..32767) -> image-layout row (b*4096 + l)
__device__ __forceinline__ int map_win(int m, int shift) {
    int n = m & 63, w = m >> 6;
    int b = w >> 6, ww = w & 63;
    int hh = ((ww >> 3) * 8 + (n >> 3) + shift) & 63;
    int wc = ((ww & 7) * 8 + (n & 7) + shift) & 63;
    return (b << 12) + (hh << 6) + wc;
}

// ---------------- small kernels ----------------

// all 4 weight tensors -> one contiguous bf16 region
__global__ void f2bf4_kernel(const float* __restrict__ s0, const float* __restrict__ s1,
                             const float* __restrict__ s2, const float* __restrict__ s3,
                             unsigned short* __restrict__ dst) {
    int i = blockIdx.x * 256 + threadIdx.x;
    const float* s; int off;
    if (i < 884736)       { s = s0; off = 0; }
    else if (i < 1179648) { s = s1; off = 884736; }
    else if (i < 2359296) { s = s2; off = 1179648; }
    else                  { s = s3; off = 2359296; }
    dst[i] = f2bf(s[i - off]);
}

__global__ void silu_kernel(const float* __restrict__ emb,
                            float* __restrict__ out, int n) {
    int i = blockIdx.x * 256 + threadIdx.x;
    if (i < n) { float e = emb[i]; out[i] = e / (1.0f + expf(-e)); }
}

__global__ __launch_bounds__(64) void ada_kernel(
    const float* __restrict__ se,           // [8][384] silu(emb)
    const float* __restrict__ ada_w,        // [2][2304][384]
    const float* __restrict__ ada_b,        // [2][2304]
    float* __restrict__ ada_out)            // [2][8][2304]
{
    int j = blockIdx.x;
    int layer = blockIdx.y;
    int t = threadIdx.x;
    const float* wr = ada_w + ((long)layer * 2304 + j) * 384;
    float w[6];
#pragma unroll
    for (int q = 0; q < 6; q++) w[q] = wr[t + 64 * q];
    float bias = ada_b[layer * 2304 + j];
    for (int b = 0; b < 8; b++) {
        float p = 0.f;
#pragma unroll
        for (int q = 0; q < 6; q++) p += se[b * 384 + t + 64 * q] * w[q];
#pragma unroll
        for (int o = 32; o > 0; o >>= 1) p += __shfl_xor(p, o);
        if (t == 0) ada_out[((long)layer * 8 + b) * 2304 + j] = p + bias;
    }
}

// LayerNorm + adaLN modulate: h = LN(x)*(1+sc) + sh; one wave per row, 4 rows/block
__global__ __launch_bounds__(256) void ln_mod_kernel(
    const float* __restrict__ x, const float* __restrict__ ada,
    unsigned short* __restrict__ h, int sh_off, int sc_off)
{
    int row = blockIdx.x * 4 + (threadIdx.x >> 6);
    int b = row >> 12;
    int t = threadIdx.x & 63;
    const float* xr = x + (long)row * 384;
    float v[6];
    float s = 0.f;
#pragma unroll
    for (int j = 0; j < 6; j++) { v[j] = xr[t + 64 * j]; s += v[j]; }
#pragma unroll
    for (int o = 32; o > 0; o >>= 1) s += __shfl_xor(s, o);
    float mean = s * (1.0f / 384.0f);
    float s2 = 0.f;
#pragma unroll
    for (int j = 0; j < 6; j++) { float d = v[j] - mean; s2 += d * d; }
#pragma unroll
    for (int o = 32; o > 0; o >>= 1) s2 += __shfl_xor(s2, o);
    float rstd = rsqrtf(s2 * (1.0f / 384.0f) + 1e-6f);
    const float* adab = ada + (long)b * 2304;
#pragma unroll
    for (int j = 0; j < 6; j++) {
        int c = t + 64 * j;
        float val = (v[j] - mean) * rstd * (1.0f + adab[sc_off + c]) + adab[sh_off + c];
        h[(long)row * 384 + c] = f2bf(val);
    }
}

// ---------------- GEMM: out[M,N] = A[M,K] @ W[N,K]^T + bias ----------------
// 128x128 tile, BK=64; global_load_lds width-16 with XOR K-chunk swizzle;
// XCD-aware block swizzle (m-tiles partitioned per XCD, n-tile fastest);
// epilogue staged through LDS for vectorized global write-out.

template <int EPI, bool GATHER, bool RESINIT>
__global__ __launch_bounds__(256) void gemm128(
    const unsigned short* __restrict__ A,
    const unsigned short* __restrict__ W,
    const float* __restrict__ bias,
    unsigned short* __restrict__ out,
    float* __restrict__ xres,
    const float* __restrict__ xbase,
    const float* __restrict__ gvec,
    int M, int N, int K, int shift)
{
    __shared__ __align__(16) unsigned short Sh[17408];  // 34816 B
    unsigned short* As = Sh;          // [128*64]
    unsigned short* Bs = Sh + 8192;   // [128*64]

    const int tid = threadIdx.x;
    const int wv = tid >> 6, lane = tid & 63;

    // XCD swizzle: linear id -> (xcd = lin&7); within an XCD n-tile runs fastest
    // so all n-blocks of one m-tile share that XCD's L2 for the A-tile.
    const int nx = gridDim.x, ny = gridDim.y;
    const int lin = blockIdx.y * nx + blockIdx.x;
    const int xcd = lin & 7, p = lin >> 3;
    const int m0 = (xcd * (ny >> 3) + p / nx) * 128;
    const int n0 = (p % nx) * 128;

    // staging: lane -> (r8 = lane>>3, c = lane&7); global chunk c^r8 so that
    // LDS slot (row, pc) holds global chunk pc ^ (row&7).
    const int r8 = lane >> 3;
    const int cofs = ((lane & 7) ^ r8) * 8;
    long arow[4], brow[4];
#pragma unroll
    for (int t = 0; t < 4; t++) {
        int rl = wv * 32 + t * 8 + r8;
        arow[t] = GATHER ? (long)map_win(m0 + rl, shift) : (long)(m0 + rl);
        brow[t] = (long)(n0 + rl);
    }

    const int wm = (wv >> 1) * 64, wn = (wv & 1) * 64;
    const int l16 = lane & 15, quad = lane >> 4;
    const int swz = l16 & 7;

    f32x4 acc[4][4] = {};

    for (int k0 = 0; k0 < K; k0 += 64) {
#pragma unroll
        for (int t = 0; t < 4; t++) {
            async_cp16(A + arow[t] * K + k0 + cofs, As + (wv * 32 + t * 8) * 64);
            async_cp16(W + brow[t] * K + k0 + cofs, Bs + (wv * 32 + t * 8) * 64);
        }
        __syncthreads();

#pragma unroll
        for (int kk = 0; kk < 2; kk++) {
            bf16x8 af[4], bfr[4];
#pragma unroll
            for (int i = 0; i < 4; i++)
                af[i] = *(const bf16x8*)&As[(wm + i * 16 + l16) * 64 +
                                            (((kk * 4 + quad) ^ swz) * 8)];
#pragma unroll
            for (int j = 0; j < 4; j++)
                bfr[j] = *(const bf16x8*)&Bs[(wn + j * 16 + l16) * 64 +
                                             (((kk * 4 + quad) ^ swz) * 8)];
#pragma unroll
            for (int i = 0; i < 4; i++)
#pragma unroll
                for (int j = 0; j < 4; j++)
                    acc[i][j] = __builtin_amdgcn_mfma_f32_16x16x32_bf16(af[i], bfr[j], acc[i][j], 0, 0, 0);
        }
        __syncthreads();
    }

    // ---- epilogue: stage C tile (bias/gelu applied) as bf16 in LDS ----
    float bv[4];
#pragma unroll
    for (int j = 0; j < 4; j++) bv[j] = bias[n0 + wn + j * 16 + l16];

    unsigned short* Cs = Sh;  // [128][136]
#pragma unroll
    for (int i = 0; i < 4; i++)
#pragma unroll
        for (int j = 0; j < 4; j++)
#pragma unroll
            for (int r = 0; r < 4; r++) {
                float v = acc[i][j][r] + bv[j];
                if constexpr (EPI == EPI_GELU) v = gelu_f(v);
                Cs[(wm + i * 16 + quad * 4 + r) * 136 + wn + j * 16 + l16] = f2bf(v);
            }
    __syncthreads();

#pragma unroll
    for (int kseg = 0; kseg < 8; kseg++) {
        int s = tid + 256 * kseg;
        int row = s >> 4, c8 = (s & 15) << 3;
        bf16x8 val = *(const bf16x8*)&Cs[row * 136 + c8];
        if constexpr (EPI == EPI_STORE || EPI == EPI_GELU) {
            *(bf16x8*)&out[(long)(m0 + row) * N + n0 + c8] = val;
        } else {
            long dst = (EPI == EPI_RES_WIN) ? (long)map_win(m0 + row, shift)
                                            : (long)(m0 + row);
            float* xrow = xres + dst * 384 + n0 + c8;
            const float* grow = gvec + (long)(dst >> 12) * 2304 + n0 + c8;
#pragma unroll
            for (int e = 0; e < 8; e++) {
                float v = (float)val[e];
                float base;
                if constexpr (RESINIT) base = xbase[dst * 384 + n0 + c8 + e];
                else                   base = xrow[e];
                xrow[e] = base + grow[e] * v;
            }
        }
    }
}

// ---------------- MFMA attention: one wave per (window, head), 4 heads/block ----

__device__ __forceinline__ int reg3(int p) { return (p < 56) ? 0 : ((p < 60) ? 1 : 2); }

__global__ __launch_bounds__(256) void attn_kernel(
    const unsigned short* __restrict__ qkv,        // [32768][1152] window layout, bf16
    const float* __restrict__ bias_table,          // layer base [225][12], f32
    unsigned short* __restrict__ out,              // [32768][384] window layout, bf16
    int shift)
{
    __shared__ unsigned short Pl[4][64 * 68];   // P matrix, padded stride 68
    __shared__ unsigned short VTl[4][32 * 68];  // V^T, padded stride 68

    const int wv = threadIdx.x >> 6, lane = threadIdx.x & 63;
    const int head = blockIdx.x * 4 + wv;    // grid.x = 3
    const int win = blockIdx.y;              // 0..511
    const int l16 = lane & 15, quad = lane >> 4;

    unsigned short* P = Pl[wv];
    unsigned short* vt = VTl[wv];

    const long base = (long)win * 64 * 1152 + head * 32;

    bf16x8 qf[4], kf[4];
#pragma unroll
    for (int i = 0; i < 4; i++) {
        qf[i] = *(const bf16x8*)&qkv[base + (long)(i * 16 + l16) * 1152 + quad * 8];
        kf[i] = *(const bf16x8*)&qkv[base + 384 + (long)(i * 16 + l16) * 1152 + quad * 8];
    }
    {
        const uint4* vp = (const uint4*)&qkv[base + 768 + (long)lane * 1152];
#pragma unroll
        for (int c4 = 0; c4 < 4; c4++) {
            uint4 v = vp[c4];
            unsigned int u[4] = {v.x, v.y, v.z, v.w};
#pragma unroll
            for (int e = 0; e < 4; e++) {
                vt[(c4 * 8 + e * 2) * 68 + lane]     = (unsigned short)(u[e] & 0xffffu);
                vt[(c4 * 8 + e * 2 + 1) * 68 + lane] = (unsigned short)(u[e] >> 16);
            }
        }
    }

    // S = Q @ K^T
    f32x4 sacc[4][4] = {};
#pragma unroll
    for (int i = 0; i < 4; i++)
#pragma unroll
        for (int j = 0; j < 4; j++)
            sacc[i][j] = __builtin_amdgcn_mfma_f32_16x16x32_bf16(qf[i], kf[j], sacc[i][j], 0, 0, 0);

    const float scale = 0.17677669529663687f;  // 1/sqrt(32)
    const int ww = win & 63, wi = ww >> 3, wj = ww & 7;

#pragma unroll
    for (int i = 0; i < 4; i++) {
#pragma unroll
        for (int r = 0; r < 4; r++) {
            int n = i * 16 + quad * 4 + r;
            int nr = n >> 3, nc = n & 7;
            int labq = (shift > 0) ? reg3(wi * 8 + nr) * 3 + reg3(wj * 8 + nc) : 0;
            float v[4];
#pragma unroll
            for (int j = 0; j < 4; j++) {
                int m = j * 16 + l16;
                int mr = m >> 3, mc = m & 7;
                float s = sacc[i][j][r] * scale +
                          bias_table[((nr - mr + 7) * 15 + (nc - mc + 7)) * 12 + head];
                if (shift > 0) {
                    int labm = reg3(wi * 8 + mr) * 3 + reg3(wj * 8 + mc);
                    if (labm != labq) s -= 100.0f;
                }
                v[j] = s;
            }
            float mx = fmaxf(fmaxf(v[0], v[1]), fmaxf(v[2], v[3]));
#pragma unroll
            for (int o = 1; o < 16; o <<= 1) mx = fmaxf(mx, __shfl_xor(mx, o));
            float sum = 0.f;
#pragma unroll
            for (int j = 0; j < 4; j++) { v[j] = __expf(v[j] - mx); sum += v[j]; }
#pragma unroll
            for (int o = 1; o < 16; o <<= 1) sum += __shfl_xor(sum, o);
            float inv = 1.0f / sum;
#pragma unroll
            for (int j = 0; j < 4; j++)
                P[n * 68 + j * 16 + l16] = f2bf(v[j] * inv);
        }
    }
    __syncthreads();

    // O = P @ V
    f32x4 oacc[4][2] = {};
#pragma unroll
    for (int kt = 0; kt < 2; kt++) {
        bf16x8 pf[4], vf[2];
#pragma unroll
        for (int i = 0; i < 4; i++)
            pf[i] = *(const bf16x8*)&P[(i * 16 + l16) * 68 + kt * 32 + quad * 8];
#pragma unroll
        for (int jt = 0; jt < 2; jt++)
            vf[jt] = *(const bf16x8*)&vt[(jt * 16 + l16) * 68 + kt * 32 + quad * 8];
#pragma unroll
        for (int i = 0; i < 4; i++)
#pragma unroll
            for (int jt = 0; jt < 2; jt++)
                oacc[i][jt] = __builtin_amdgcn_mfma_f32_16x16x32_bf16(pf[i], vf[jt], oacc[i][jt], 0, 0, 0);
    }

#pragma unroll
    for (int i = 0; i < 4; i++)
#pragma unroll
        for (int jt = 0; jt < 2; jt++)
#pragma unroll
            for (int r = 0; r < 4; r++) {
                int row = i * 16 + quad * 4 + r;
                int col = jt * 16 + l16;
                out[((long)win * 64 + row) * 384 + head * 32 + col] = f2bf(oacc[i][jt][r]);
            }
}

// ---------------- launch ----------------

extern "C" void kernel_launch(void* const* d_in, const int* in_sizes, int n_in,
                              void* d_out, int out_size, void* d_ws, size_t ws_size,
                              hipStream_t stream) {
    const float* x_in   = (const float*)d_in[0];
    const float* emb    = (const float*)d_in[3];
    const float* qkv_w  = (const float*)d_in[4];
    const float* qkv_b  = (const float*)d_in[5];
    const float* proj_w = (const float*)d_in[6];
    const float* proj_b = (const float*)d_in[7];
    const float* ff1_w  = (const float*)d_in[8];
    const float* ff1_b  = (const float*)d_in[9];
    const float* ff2_w  = (const float*)d_in[10];
    const float* ff2_b  = (const float*)d_in[11];
    const float* ada_w  = (const float*)d_in[12];
    const float* ada_b  = (const float*)d_in[13];
    const float* bias_t = (const float*)d_in[14];

    char* ws = (char*)d_ws;
    unsigned short* h_buf   = (unsigned short*)ws;               // 25,165,824
    unsigned short* big_buf = (unsigned short*)(ws + 25165824);  // 100,663,296 (qkv & ff1 share)
    unsigned short* wqkv    = (unsigned short*)(ws + 125829120); // 1,769,472
    unsigned short* wproj   = (unsigned short*)(ws + 127598592); // 589,824
    unsigned short* wff1    = (unsigned short*)(ws + 128188416); // 2,359,296
    unsigned short* wff2    = (unsigned short*)(ws + 130547712); // 2,359,296
    float*          ada_out = (float*)(ws + 132907008);          // 147,456
    float*          se      = (float*)(ws + 133054464);          // 12,288

    float* x_acc = (float*)d_out;  // f32 residual stream lives in d_out

    const int M = 32768;

    // all weights -> contiguous bf16 region starting at wqkv (3,538,944 elems)
    f2bf4_kernel<<<13824, 256, 0, stream>>>(qkv_w, proj_w, ff1_w, ff2_w, wqkv);

    silu_kernel<<<(3072 + 255) / 256, 256, 0, stream>>>(emb, se, 3072);
    ada_kernel<<<dim3(2304, 2), 64, 0, stream>>>(se, ada_w, ada_b, ada_out);

    for (int layer = 0; layer < 2; layer++) {
        const int shift = layer ? 4 : 0;
        const float* ada_l = ada_out + (long)layer * 8 * 2304;
        // splits: sh_sa 0, sc_sa 384, g_sa 768, sh_ff 1152, sc_ff 1536, g_ff 1920

        ln_mod_kernel<<<M / 4, 256, 0, stream>>>(layer == 0 ? x_in : x_acc,
                                                 ada_l, h_buf, 0, 384);

        gemm128<EPI_STORE, true, false><<<dim3(9, 256), 256, 0, stream>>>(
            h_buf, wqkv + (long)layer * 1152 * 384, qkv_b + layer * 1152,
            big_buf, nullptr, nullptr, nullptr, M, 1152, 384, shift);

        attn_kernel<<<dim3(3, 512), 256, 0, stream>>>(
            big_buf, bias_t + layer * 225 * 12, h_buf, shift);

        if (layer == 0) {
            gemm128<EPI_RES_WIN, false, true><<<dim3(3, 256), 256, 0, stream>>>(
                h_buf, wproj, proj_b,
                nullptr, x_acc, x_in, ada_l + 768, M, 384, 384, shift);
        } else {
            gemm128<EPI_RES_WIN, false, false><<<dim3(3, 256), 256, 0, stream>>>(
                h_buf, wproj + (long)384 * 384, proj_b + 384,
                nullptr, x_acc, nullptr, ada_l + 768, M, 384, 384, shift);
        }

        ln_mod_kernel<<<M / 4, 256, 0, stream>>>(x_acc, ada_l, h_buf, 1152, 1536);

        gemm128<EPI_GELU, false, false><<<dim3(12, 256), 256, 0, stream>>>(
            h_buf, wff1 + (long)layer * 1536 * 384, ff1_b + layer * 1536,
            big_buf, nullptr, nullptr, nullptr, M, 1536, 384, 0);

        gemm128<EPI_RES_ID, false, false><<<dim3(3, 256), 256, 0, stream>>>(
            big_buf, wff2 + (long)layer * 384 * 1536, ff2_b + layer * 384,
            nullptr, x_acc, nullptr, ada_l + 1920, M, 384, 1536, 0);
    }
}